// Round 1
// 267.555 us; speedup vs baseline: 1.1022x; 1.1022x over previous
//
#include <hip/hip_runtime.h>
#include <stdint.h>

#define N_COLS 524288
#define N_ROWS 64               // fixed by setup_inputs (B=64)
#define N_PRIMES 168
#define BLOCK 256
#define COLS_PER_BLOCK 1024     // 4 columns per thread
#define CG_TOTAL (N_COLS / 4)   // 131072 float4 column-groups per row

// primes below 1000 — compile-time constants so % p lowers to magic-multiply
static constexpr uint32_t PRIMES[N_PRIMES] = {
      2,   3,   5,   7,  11,  13,  17,  19,  23,  29,
     31,  37,  41,  43,  47,  53,  59,  61,  67,  71,
     73,  79,  83,  89,  97, 101, 103, 107, 109, 113,
    127, 131, 137, 139, 149, 151, 157, 163, 167, 173,
    179, 181, 191, 193, 197, 199, 211, 223, 227, 229,
    233, 239, 241, 251, 257, 263, 269, 271, 277, 281,
    283, 293, 307, 311, 313, 317, 331, 337, 347, 349,
    353, 359, 367, 373, 379, 383, 389, 397, 401, 409,
    419, 421, 431, 433, 439, 443, 449, 457, 461, 463,
    467, 479, 487, 491, 499, 503, 509, 521, 523, 541,
    547, 557, 563, 569, 571, 577, 587, 593, 599, 601,
    607, 613, 617, 619, 631, 641, 643, 647, 653, 659,
    661, 673, 677, 683, 691, 701, 709, 719, 727, 733,
    739, 743, 751, 757, 761, 769, 773, 787, 797, 809,
    811, 821, 823, 827, 829, 839, 853, 857, 859, 863,
    877, 881, 883, 887, 907, 911, 919, 929, 937, 941,
    947, 953, 967, 971, 977, 983, 991, 997
};

// Single fused kernel. Block b owns columns [1024*b, 1024*b + 1024).
//
// Mask phase: thread t computes w/b for columns {c0, c0+256, c0+512, c0+768}
// where c0 = 1024*b + t. Consecutive lanes -> consecutive (k mod p) table
// indices, so every gather is stride-1 (<=4 cache lines per wave-load).
// All primes are compile-time constants: `% p` is a magic-multiply and the
// spread step uses d = 256 % p (compile-time) with a single conditional wrap.
//
// LDS transpose (8 KB, one barrier): wl[j] = mask for column 1024*b + j, so
// thread t can read a float4 of 4 *contiguous* columns for the stream phase.
//
// Stream phase: identical to the old bwl_prime_stream inner loop — float4
// load -> fma -> store, 64 rows per thread, fully coalesced 1 KB wave-loads.
__global__ __launch_bounds__(BLOCK) void bwl_prime_fused_v2(
    const float* __restrict__ x,
    const float* __restrict__ kern,
    const float* __restrict__ bias,
    float* __restrict__ out)
{
    __shared__ float wl[COLS_PER_BLOCK];
    __shared__ float bl[COLS_PER_BLOCK];

    const int t = threadIdx.x;
    const uint32_t col0 = (uint32_t)blockIdx.x * COLS_PER_BLOCK + (uint32_t)t;

    float w0 = 0.f, w1 = 0.f, w2 = 0.f, w3 = 0.f;
    float b0 = 0.f, b1 = 0.f, b2 = 0.f, b3 = 0.f;

#pragma unroll
    for (int i = 0; i < N_PRIMES; ++i) {
        const uint32_t p = PRIMES[i];       // compile-time constant
        const int off = i * 1000;           // compile-time constant
        const uint32_t d = 256u % p;        // compile-time constant
        uint32_t m = col0 % p;              // magic-multiply
        w0 += kern[off + (int)m];  b0 += bias[off + (int)m];
        m += d; if (m >= p) m -= p;
        w1 += kern[off + (int)m];  b1 += bias[off + (int)m];
        m += d; if (m >= p) m -= p;
        w2 += kern[off + (int)m];  b2 += bias[off + (int)m];
        m += d; if (m >= p) m -= p;
        w3 += kern[off + (int)m];  b3 += bias[off + (int)m];
    }

    // LDS transpose: spread-column registers -> column-ordered table.
    // Writes are stride-1 across lanes within each group of 256 -> no bank
    // conflicts; reads are ds_read_b128 at 4*t -> standard 2-way (free).
    wl[t]       = w0;  bl[t]       = b0;
    wl[t + 256] = w1;  bl[t + 256] = b1;
    wl[t + 512] = w2;  bl[t + 512] = b2;
    wl[t + 768] = w3;  bl[t + 768] = b3;
    __syncthreads();

    const float4 wv = ((const float4*)wl)[t];
    const float4 bv = ((const float4*)bl)[t];

    const int cg = blockIdx.x * BLOCK + t;   // float4 column-group index
    const float4* __restrict__ x4 = (const float4*)x;
    float4* __restrict__ o4 = (float4*)out;

#pragma unroll 8
    for (int r = 0; r < N_ROWS; ++r) {
        const size_t off = (size_t)r * CG_TOTAL + cg;
        float4 xv = x4[off];
        float4 ov;
        ov.x = fmaf(xv.x, wv.x, bv.x);
        ov.y = fmaf(xv.y, wv.y, bv.y);
        ov.z = fmaf(xv.z, wv.z, bv.z);
        ov.w = fmaf(xv.w, wv.w, bv.w);
        o4[off] = ov;
    }
}

extern "C" void kernel_launch(void* const* d_in, const int* in_sizes, int n_in,
                              void* d_out, int out_size, void* d_ws, size_t ws_size,
                              hipStream_t stream) {
    (void)in_sizes; (void)n_in; (void)d_ws; (void)ws_size;
    const float* x    = (const float*)d_in[0];
    const float* kern = (const float*)d_in[1];
    const float* bias = (const float*)d_in[2];
    float* out = (float*)d_out;

    // One launch: 512 blocks x 256 threads, each block owns 1024 columns.
    bwl_prime_fused_v2<<<N_COLS / COLS_PER_BLOCK, BLOCK, 0, stream>>>(
        x, kern, bias, out);
}

// Round 2
// 266.953 us; speedup vs baseline: 1.1047x; 1.0023x over previous
//
#include <hip/hip_runtime.h>
#include <stdint.h>

#define N_COLS 524288
#define N_ROWS 64               // fixed by setup_inputs (B=64)
#define N_PRIMES 168
#define BLOCK 256
#define ROW_CHUNKS 8            // stream kernel grid.y; 8 rows per thread
#define CG_TOTAL (N_COLS / 4)   // 131072 float4 column-groups per row

// primes below 1000 — compile-time constants so % p lowers to magic-multiply
static constexpr uint32_t PRIMES[N_PRIMES] = {
      2,   3,   5,   7,  11,  13,  17,  19,  23,  29,
     31,  37,  41,  43,  47,  53,  59,  61,  67,  71,
     73,  79,  83,  89,  97, 101, 103, 107, 109, 113,
    127, 131, 137, 139, 149, 151, 157, 163, 167, 173,
    179, 181, 191, 193, 197, 199, 211, 223, 227, 229,
    233, 239, 241, 251, 257, 263, 269, 271, 277, 281,
    283, 293, 307, 311, 313, 317, 331, 337, 347, 349,
    353, 359, 367, 373, 379, 383, 389, 397, 401, 409,
    419, 421, 431, 433, 439, 443, 449, 457, 461, 463,
    467, 479, 487, 491, 499, 503, 509, 521, 523, 541,
    547, 557, 563, 569, 571, 577, 587, 593, 599, 601,
    607, 613, 617, 619, 631, 641, 643, 647, 653, 659,
    661, 673, 677, 683, 691, 701, 709, 719, 727, 733,
    739, 743, 751, 757, 761, 769, 773, 787, 797, 809,
    811, 821, 823, 827, 829, 839, 853, 857, 859, 863,
    877, 881, 883, 887, 907, 911, 919, 929, 937, 941,
    947, 953, 967, 971, 977, 983, 991, 997
};

// Kernel A: mask table build. One column per thread, 2048 blocks x 256
// -> 8 blocks/CU -> full 32-wave occupancy for the gather (latency) phase.
// Lanes access consecutive columns, so every table gather is stride-1
// (<=5 cache lines per wave-load); writes are perfectly coalesced floats.
// No atomics, no zero-fill, no LDS.
__global__ __launch_bounds__(BLOCK) void bwl_prime_mask_v3(
    const float* __restrict__ kern,
    const float* __restrict__ bias,
    float* __restrict__ wsw,
    float* __restrict__ wsb)
{
    const uint32_t col = blockIdx.x * BLOCK + threadIdx.x;  // 0..524287

    float w = 0.f, b = 0.f;
#pragma unroll
    for (int i = 0; i < N_PRIMES; ++i) {
        const uint32_t p = PRIMES[i];       // compile-time constant
        const int off = i * 1000;           // compile-time constant
        const uint32_t m = col % p;         // magic-multiply, no divide
        w += kern[off + (int)m];
        b += bias[off + (int)m];
    }
    wsw[col] = w;
    wsb[col] = b;
}

// Kernel B: pure streaming. grid = (512, ROW_CHUNKS) = 4096 blocks
// -> 16 blocks/CU queued, ~8 resident -> enough waves to saturate HBM.
// w/b float4 loaded once per thread (4 MB table is L2/L3-resident),
// then 8 independent load->fma->store iterations, fully unrolled so all
// 8 float4 loads are in flight.
__global__ __launch_bounds__(BLOCK) void bwl_prime_stream_v3(
    const float* __restrict__ x,
    const float4* __restrict__ wsw,
    const float4* __restrict__ wsb,
    float* __restrict__ out)
{
    const int cg = blockIdx.x * BLOCK + threadIdx.x;    // column-group
    const int r0 = blockIdx.y * (N_ROWS / ROW_CHUNKS);  // 8 rows per thread

    const float4 w = wsw[cg];
    const float4 b = wsb[cg];

    const float4* __restrict__ x4 = (const float4*)x;
    float4* __restrict__ o4 = (float4*)out;

#pragma unroll
    for (int i = 0; i < N_ROWS / ROW_CHUNKS; ++i) {
        const size_t off = (size_t)(r0 + i) * CG_TOTAL + cg;
        float4 xv = x4[off];
        float4 ov;
        ov.x = fmaf(xv.x, w.x, b.x);
        ov.y = fmaf(xv.y, w.y, b.y);
        ov.z = fmaf(xv.z, w.z, b.z);
        ov.w = fmaf(xv.w, w.w, b.w);
        o4[off] = ov;
    }
}

// Fallback single-kernel (round-1 fused) if workspace is unavailable.
__global__ __launch_bounds__(BLOCK) void bwl_prime_fused_v2(
    const float* __restrict__ x,
    const float* __restrict__ kern,
    const float* __restrict__ bias,
    float* __restrict__ out)
{
    __shared__ float wl[1024];
    __shared__ float bl[1024];

    const int t = threadIdx.x;
    const uint32_t col0 = (uint32_t)blockIdx.x * 1024u + (uint32_t)t;

    float w0 = 0.f, w1 = 0.f, w2 = 0.f, w3 = 0.f;
    float b0 = 0.f, b1 = 0.f, b2 = 0.f, b3 = 0.f;

#pragma unroll
    for (int i = 0; i < N_PRIMES; ++i) {
        const uint32_t p = PRIMES[i];
        const int off = i * 1000;
        const uint32_t d = 256u % p;
        uint32_t m = col0 % p;
        w0 += kern[off + (int)m];  b0 += bias[off + (int)m];
        m += d; if (m >= p) m -= p;
        w1 += kern[off + (int)m];  b1 += bias[off + (int)m];
        m += d; if (m >= p) m -= p;
        w2 += kern[off + (int)m];  b2 += bias[off + (int)m];
        m += d; if (m >= p) m -= p;
        w3 += kern[off + (int)m];  b3 += bias[off + (int)m];
    }

    wl[t]       = w0;  bl[t]       = b0;
    wl[t + 256] = w1;  bl[t + 256] = b1;
    wl[t + 512] = w2;  bl[t + 512] = b2;
    wl[t + 768] = w3;  bl[t + 768] = b3;
    __syncthreads();

    const float4 wv = ((const float4*)wl)[t];
    const float4 bv = ((const float4*)bl)[t];

    const int cg = blockIdx.x * BLOCK + t;
    const float4* __restrict__ x4 = (const float4*)x;
    float4* __restrict__ o4 = (float4*)out;

#pragma unroll 8
    for (int r = 0; r < N_ROWS; ++r) {
        const size_t off = (size_t)r * CG_TOTAL + cg;
        float4 xv = x4[off];
        float4 ov;
        ov.x = fmaf(xv.x, wv.x, bv.x);
        ov.y = fmaf(xv.y, wv.y, bv.y);
        ov.z = fmaf(xv.z, wv.z, bv.z);
        ov.w = fmaf(xv.w, wv.w, bv.w);
        o4[off] = ov;
    }
}

extern "C" void kernel_launch(void* const* d_in, const int* in_sizes, int n_in,
                              void* d_out, int out_size, void* d_ws, size_t ws_size,
                              hipStream_t stream) {
    (void)in_sizes; (void)n_in; (void)out_size;
    const float* x    = (const float*)d_in[0];
    const float* kern = (const float*)d_in[1];
    const float* bias = (const float*)d_in[2];
    float* out = (float*)d_out;

    const size_t need = (size_t)2 * N_COLS * sizeof(float);  // 4 MB

    if (ws_size >= need) {
        float* wsw = (float*)d_ws;
        float* wsb = wsw + N_COLS;

        // A: build w/b tables — full-occupancy gather kernel, no atomics.
        bwl_prime_mask_v3<<<N_COLS / BLOCK, BLOCK, 0, stream>>>(
            kern, bias, wsw, wsb);

        // B: stream x -> out with 4096 blocks so HBM saturates.
        dim3 sgrid(CG_TOTAL / BLOCK, ROW_CHUNKS);
        bwl_prime_stream_v3<<<sgrid, BLOCK, 0, stream>>>(
            x, (const float4*)wsw, (const float4*)wsb, out);
    } else {
        bwl_prime_fused_v2<<<N_COLS / 1024, BLOCK, 0, stream>>>(
            x, kern, bias, out);
    }
}